// Round 9
// baseline (40.828 us; speedup 1.0000x reference)
//
#include <hip/hip_runtime.h>
#include <hip/hip_fp16.h>

#define B_  8
#define N_  100
#define T_  16
#define TP_ 15     // T-1 output steps (pred_steps == 1)
#define D_  4
#define H_  64
#define E_  9900   // N*(N-1)
#define NG2 7      // groups of 16 receivers (last group has 4)
#define ROWS 12000 // B*TP*N

// ---- d_ws layout (bytes) ----
#define WS_RTT 0u          // f32 [8][100][112] receiver-major rel_type    358,400
#define WS_UBF 358400u     // f16 [120][100][72] sender pre-act (+pad)   1,730,560
#define WS_W2F 2088960u    // f16 8 MFMA frags of W2^T (msg MLP2)            8,192
#define WS_W1F 2097152u    // f16 12 MFMA frags of W1out^T (K=96 padded)    12,288
#define WS_W2B 2109440u    // f16 8 MFMA frags of W2out^T                    8,192
#define WS_W3F 2117632u    // f16 [16][16] W3out per-lane pack               2,048
                           // total 2,119,680 B

typedef __attribute__((ext_vector_type(8))) _Float16 f16x8;
typedef __attribute__((ext_vector_type(4))) float f32x4;

__device__ __forceinline__ void gload_lds16(const void* g, void* lds) {
    __builtin_amdgcn_global_load_lds(
        (const __attribute__((address_space(1))) void*)g,
        (__attribute__((address_space(3))) void*)lds, 16, 0, 0);
}

// relu(u+v) on 8 packed f16 -> 4x v_pk_add_f16 + 4x v_pk_max_f16
__device__ __forceinline__ f16x8 relu_add8(uint4 u, uint4 v) {
    const f16x8 a = __builtin_bit_cast(f16x8, u);
    const f16x8 b = __builtin_bit_cast(f16x8, v);
    const f16x8 s = a + b;
    const f16x8 z = (f16x8)(_Float16)0;
    return __builtin_elementwise_max(s, z);
}

// ==================== prep: u rows, rtt gather, weight frags ================
__global__ __launch_bounds__(256)
void nri_prep(const float* __restrict__ x, const float* __restrict__ rel,
              const float* __restrict__ w1, const float* __restrict__ w2,
              const float* __restrict__ f1w, const float* __restrict__ f2w,
              const float* __restrict__ f3w,
              __half* __restrict__ ubf, float* __restrict__ rtt,
              __half* __restrict__ w2f, __half* __restrict__ w1f,
              __half* __restrict__ w2b, __half* __restrict__ w3f)
{
    const int lane = threadIdx.x & 63;
    const int wid  = blockIdx.x * 4 + (threadIdx.x >> 6);

    if (wid < ROWS) {                       // u row per (b,t,node)
        const int nn = wid % N_;
        const int bt = wid / N_;
        const int t  = bt % TP_;
        const int b  = bt / TP_;
        const float4 ws4 = *(const float4*)(w1 + lane * 8);
        const float4 xv  = *(const float4*)(x + (((size_t)b * N_ + nn) * T_ + t) * D_);
        ubf[(size_t)bt * 7200 + nn * 72 + lane] =
            __float2half(ws4.x * xv.x + ws4.y * xv.y + ws4.z * xv.z + ws4.w * xv.w);
    } else if (wid < ROWS + B_ * N_) {      // rtt row per (b, receiver n)
        const int idx = wid - ROWS;
        const int n = idx % N_;
        const int b = idx / N_;
        float* dst = rtt + (size_t)idx * 112;
        const int ia  = lane + (lane >= n ? 1 : 0);
        const int eda = ia * (N_ - 1) + (n < ia ? n : n - 1);
        dst[lane] = rel[((size_t)b * E_ + eda) * 2 + 1];
        if (lane < 48) {
            const int e2 = 64 + lane;
            float rv = 0.f;
            if (e2 < N_ - 1) {
                const int ib  = e2 + (e2 >= n ? 1 : 0);
                const int edb = ib * (N_ - 1) + (n < ib ? n : n - 1);
                rv = rel[((size_t)b * E_ + edb) * 2 + 1];
            }
            dst[64 + lane] = rv;
        }
    } else {                                // weight-fragment packing waves
        const int fid = wid - (ROWS + B_ * N_);
        const int g16 = lane & 15, q = lane >> 4;
        unsigned short h[8];
        if (fid < 8) {                      // W2^T frags (msg MLP2)
            const int s = fid >> 2, nt = fid & 3;
            const int g = nt * 16 + g16;
            #pragma unroll
            for (int j = 0; j < 8; ++j)
                h[j] = __half_as_ushort(__float2half(
                    w2[(size_t)g * 64 + s * 32 + q * 8 + j]));
            uint4 pv; pv.x = h[0] | ((unsigned)h[1] << 16); pv.y = h[2] | ((unsigned)h[3] << 16);
                      pv.z = h[4] | ((unsigned)h[5] << 16); pv.w = h[6] | ((unsigned)h[7] << 16);
            *(uint4*)(w2f + fid * 512 + lane * 8) = pv;
        } else if (fid < 20) {              // W1out^T frags, K=96: [agg|x|0]
            const int f = fid - 8;
            const int s = f >> 2, nt = f & 3;
            const int g = nt * 16 + g16;
            #pragma unroll
            for (int j = 0; j < 8; ++j) {
                const int k = s * 32 + q * 8 + j;
                float v = 0.f;
                if (k < 64)       v = f1w[(size_t)g * 68 + 4 + k];
                else if (k < 68)  v = f1w[(size_t)g * 68 + (k - 64)];
                h[j] = __half_as_ushort(__float2half(v));
            }
            uint4 pv; pv.x = h[0] | ((unsigned)h[1] << 16); pv.y = h[2] | ((unsigned)h[3] << 16);
                      pv.z = h[4] | ((unsigned)h[5] << 16); pv.w = h[6] | ((unsigned)h[7] << 16);
            *(uint4*)(w1f + f * 512 + lane * 8) = pv;
        } else if (fid < 28) {              // W2out^T frags
            const int f = fid - 20;
            const int s = f >> 2, nt = f & 3;
            const int g = nt * 16 + g16;
            #pragma unroll
            for (int j = 0; j < 8; ++j)
                h[j] = __half_as_ushort(__float2half(
                    f2w[(size_t)g * 64 + s * 32 + q * 8 + j]));
            uint4 pv; pv.x = h[0] | ((unsigned)h[1] << 16); pv.y = h[2] | ((unsigned)h[3] << 16);
                      pv.z = h[4] | ((unsigned)h[5] << 16); pv.w = h[6] | ((unsigned)h[7] << 16);
            *(uint4*)(w2b + f * 512 + lane * 8) = pv;
        } else if (fid == 28) {             // W3 per-lane pack [col][nt*4+d]
            unsigned short hh[16];
            #pragma unroll
            for (int nt = 0; nt < 4; ++nt)
                #pragma unroll
                for (int d = 0; d < 4; ++d)
                    hh[nt * 4 + d] = __half_as_ushort(__float2half(
                        f3w[d * 64 + nt * 16 + g16]));
            uint4 p0, p1;
            p0.x = hh[0] | ((unsigned)hh[1] << 16);  p0.y = hh[2] | ((unsigned)hh[3] << 16);
            p0.z = hh[4] | ((unsigned)hh[5] << 16);  p0.w = hh[6] | ((unsigned)hh[7] << 16);
            p1.x = hh[8] | ((unsigned)hh[9] << 16);  p1.y = hh[10] | ((unsigned)hh[11] << 16);
            p1.z = hh[12] | ((unsigned)hh[13] << 16); p1.w = hh[14] | ((unsigned)hh[15] << 16);
            *(uint4*)(w3f + lane * 16) = p0;
            *(uint4*)(w3f + lane * 16 + 8) = p1;
        }
    }
}

// ============ fused main: message MLP + aggregation + out-MLP ===============
// One block (4 waves) per (b,t, group of 16 receivers). Rounds: each wave
// computes one receiver's agg via MFMA and writes it (f16) into the [16][104]
// LDS input tile. Tail: wave 0 runs the 16-row out-MLP GEMM chain + store.
__global__ __launch_bounds__(256)
void nri_main(const __half* __restrict__ ubf, const float* __restrict__ rtt,
              const __half* __restrict__ w2f, const float* __restrict__ b2,
              const float* __restrict__ w1, const float* __restrict__ b1,
              const __half* __restrict__ w1f, const __half* __restrict__ w2b,
              const __half* __restrict__ w3f,
              const float* __restrict__ f1b, const float* __restrict__ f2b,
              const float* __restrict__ f3b,
              const float* __restrict__ x, float* __restrict__ out)
{
    __shared__ __half u_lds[7680];      // 15,360 B u tile (100 x 72 + DMA pad)
    __shared__ __half ain[16][104];     // [agg(64)|x(4)|0(28)] rows, padded
    __shared__ __half v_lds[4][72];
    __shared__ __half p1buf[16][72];

    const int tid  = threadIdx.x;
    const int lane = tid & 63;
    const int w    = tid >> 6;
    const int bid  = blockIdx.x;
    const int g  = bid % NG2;
    const int t  = (bid / NG2) % TP_;
    const int b  = bid / (NG2 * TP_);
    const int bt = b * TP_ + t;

    // u-tile DMA first: 15 x 1KB chunks
    {
        const char* gsrc = (const char*)(ubf + (size_t)bt * 7200);
        char* ldst = (char*)u_lds;
        #pragma unroll
        for (int j = 0; j < 4; ++j) {
            const int c = w + 4 * j;        // wave-uniform
            if (c < 15)
                gload_lds16(gsrc + c * 1024 + lane * 16, ldst + c * 1024);
        }
    }

    const int col = lane & 15;
    const int q   = lane >> 4;
    const int kq  = q * 8;

    // zero K-pad cols [68..96) of all 16 rows
    if (tid < 224) {
        const int r = tid / 14, u = tid % 14;
        *(unsigned*)&ain[r][68 + u * 2] = 0u;
    }

    const float4 wr4 = *(const float4*)(w1 + lane * 8 + 4);
    const float  bv1 = b1[lane];

    f16x8 bfr[8];
    #pragma unroll
    for (int f = 0; f < 8; ++f)
        bfr[f] = *(const f16x8*)((const char*)w2f + f * 1024 + lane * 16);
    float bb[4];
    #pragma unroll
    for (int nt = 0; nt < 4; ++nt) bb[nt] = b2[nt * 16 + col];

    __syncthreads();                        // u tile landed; pads zeroed

    // ---- rounds: one receiver per wave per round ----
    #pragma unroll 1
    for (int r = 0; r < 4; ++r) {
        const int n = g * 16 + r * 4 + w;
        if (n < N_) {                       // wave-uniform
            const int row = r * 4 + w;
            const float4 xr = *(const float4*)(
                x + (((size_t)b * N_ + n) * T_ + t) * D_);
            v_lds[w][lane] = __float2half(
                wr4.x * xr.x + wr4.y * xr.y + wr4.z * xr.z + wr4.w * xr.w + bv1);
            if (lane < 4) {
                const float xc = (lane == 0) ? xr.x : (lane == 1) ? xr.y
                               : (lane == 2) ? xr.z : xr.w;
                ain[row][64 + lane] = __float2half(xc);
            }
            __builtin_amdgcn_wave_barrier();
            const uint4 vv0 = *(const uint4*)&v_lds[w][kq];
            const uint4 vv1 = *(const uint4*)&v_lds[w][32 + kq];
            const float* rtp = rtt + ((size_t)b * N_ + n) * 112 + q * 4;

            float aggl[4] = {0.f, 0.f, 0.f, 0.f};
            #pragma unroll
            for (int mf = 0; mf < 7; ++mf) {
                const int e = mf * 16 + col;
                int i = e + (e >= n ? 1 : 0);
                if (i > N_ - 1) i = N_ - 1;  // pad rows masked by rt=0
                const float4 rt4 = *(const float4*)(rtp + mf * 16);
                f32x4 acc[4] = {};
                const uint4 ud0 = *(const uint4*)&u_lds[i * 72 + kq];
                f16x8 af = relu_add8(ud0, vv0);
                #pragma unroll
                for (int nt = 0; nt < 4; ++nt)
                    acc[nt] = __builtin_amdgcn_mfma_f32_16x16x32_f16(
                        af, bfr[nt], acc[nt], 0, 0, 0);
                const uint4 ud1 = *(const uint4*)&u_lds[i * 72 + 32 + kq];
                af = relu_add8(ud1, vv1);
                #pragma unroll
                for (int nt = 0; nt < 4; ++nt)
                    acc[nt] = __builtin_amdgcn_mfma_f32_16x16x32_f16(
                        af, bfr[4 + nt], acc[nt], 0, 0, 0);
                #pragma unroll
                for (int nt = 0; nt < 4; ++nt) {
                    aggl[nt] += fmaxf(acc[nt][0] + bb[nt], 0.f) * rt4.x
                              + fmaxf(acc[nt][1] + bb[nt], 0.f) * rt4.y
                              + fmaxf(acc[nt][2] + bb[nt], 0.f) * rt4.z
                              + fmaxf(acc[nt][3] + bb[nt], 0.f) * rt4.w;
                }
            }
            #pragma unroll
            for (int nt = 0; nt < 4; ++nt) {
                float p = aggl[nt];
                p += __shfl_xor(p, 16, 64);
                p += __shfl_xor(p, 32, 64);
                if (lane < 16)
                    ain[row][nt * 16 + col] = __float2half(p);
            }
        }
    }
    __syncthreads();                        // ain tile complete

    // ---- tail: out-MLP for the 16 rows on wave 0 ----
    if (w != 0) return;

    f16x8 w1r[12];
    #pragma unroll
    for (int f = 0; f < 12; ++f)
        w1r[f] = *(const f16x8*)((const char*)w1f + f * 1024 + lane * 16);
    float b1v[4];
    #pragma unroll
    for (int nt = 0; nt < 4; ++nt) b1v[nt] = f1b[nt * 16 + col];

    // GEMM1: p1 = relu([agg|x|0] @ W1^T + b1), K=96
    f32x4 acc1[4] = {};
    #pragma unroll
    for (int s = 0; s < 3; ++s) {
        const uint4 ad = *(const uint4*)&ain[col][s * 32 + kq];
        const f16x8 af = __builtin_bit_cast(f16x8, ad);
        #pragma unroll
        for (int nt = 0; nt < 4; ++nt)
            acc1[nt] = __builtin_amdgcn_mfma_f32_16x16x32_f16(
                af, w1r[s * 4 + nt], acc1[nt], 0, 0, 0);
    }
    #pragma unroll
    for (int nt = 0; nt < 4; ++nt)
        #pragma unroll
        for (int j = 0; j < 4; ++j)
            p1buf[q * 4 + j][nt * 16 + col] =
                __float2half(fmaxf(acc1[nt][j] + b1v[nt], 0.f));
    asm volatile("s_waitcnt lgkmcnt(0)" ::: "memory");
    __builtin_amdgcn_wave_barrier();

    f16x8 w2r[8];
    #pragma unroll
    for (int f = 0; f < 8; ++f)
        w2r[f] = *(const f16x8*)((const char*)w2b + f * 1024 + lane * 16);
    float b2v[4];
    #pragma unroll
    for (int nt = 0; nt < 4; ++nt) b2v[nt] = f2b[nt * 16 + col];

    // GEMM2: p2 = relu(p1 @ W2^T + b2), K=64
    f32x4 acc2[4] = {};
    #pragma unroll
    for (int s = 0; s < 2; ++s) {
        const uint4 pd = *(const uint4*)&p1buf[col][s * 32 + kq];
        const f16x8 af = __builtin_bit_cast(f16x8, pd);
        #pragma unroll
        for (int nt = 0; nt < 4; ++nt)
            acc2[nt] = __builtin_amdgcn_mfma_f32_16x16x32_f16(
                af, w2r[s * 4 + nt], acc2[nt], 0, 0, 0);
    }
    float p2v[4][4];
    #pragma unroll
    for (int nt = 0; nt < 4; ++nt)
        #pragma unroll
        for (int j = 0; j < 4; ++j)
            p2v[nt][j] = fmaxf(acc2[nt][j] + b2v[nt], 0.f);

    // p3[d] = sum_g w3[d][g] p2[g]: per-col partial, butterfly over 16 cols
    float w3v[16];
    {
        const uint4 p0 = *(const uint4*)(w3f + col * 16);
        const uint4 p1 = *(const uint4*)(w3f + col * 16 + 8);
        const unsigned* pp0 = (const unsigned*)&p0;
        const unsigned* pp1 = (const unsigned*)&p1;
        #pragma unroll
        for (int i = 0; i < 4; ++i) {
            w3v[2*i]     = __half2float(__ushort_as_half((unsigned short)(pp0[i] & 0xffff)));
            w3v[2*i + 1] = __half2float(__ushort_as_half((unsigned short)(pp0[i] >> 16)));
            w3v[8 + 2*i]     = __half2float(__ushort_as_half((unsigned short)(pp1[i] & 0xffff)));
            w3v[8 + 2*i + 1] = __half2float(__ushort_as_half((unsigned short)(pp1[i] >> 16)));
        }
    }
    const float4 b3v = *(const float4*)f3b;
    float pr[4][4];                          // [d][j]
    #pragma unroll
    for (int d = 0; d < 4; ++d)
        #pragma unroll
        for (int j = 0; j < 4; ++j) {
            float s = w3v[0 * 4 + d] * p2v[0][j] + w3v[1 * 4 + d] * p2v[1][j]
                    + w3v[2 * 4 + d] * p2v[2][j] + w3v[3 * 4 + d] * p2v[3][j];
            s += __shfl_xor(s, 1, 64);
            s += __shfl_xor(s, 2, 64);
            s += __shfl_xor(s, 4, 64);
            s += __shfl_xor(s, 8, 64);
            pr[d][j] = s;
        }

    if (col == 0) {                          // lanes 0,16,32,48: 4 rows each
        #pragma unroll
        for (int j = 0; j < 4; ++j) {
            const int rr = q * 4 + j;
            const int n  = g * 16 + rr;
            if (n < N_) {
                const float4 xv = *(const float4*)(
                    x + (((size_t)b * N_ + n) * T_ + t) * D_);
                float4 o;
                o.x = xv.x + b3v.x + pr[0][j];
                o.y = xv.y + b3v.y + pr[1][j];
                o.z = xv.z + b3v.z + pr[2][j];
                o.w = xv.w + b3v.w + pr[3][j];
                *(float4*)(out + (((size_t)b * N_ + n) * TP_ + t) * D_) = o;
            }
        }
    }
}

extern "C" void kernel_launch(void* const* d_in, const int* in_sizes, int n_in,
                              void* d_out, int out_size, void* d_ws, size_t ws_size,
                              hipStream_t stream) {
    const float* x   = (const float*)d_in[0];
    const float* rel = (const float*)d_in[1];
    // d_in[2]=rel_rec, d_in[3]=rel_send: one-hot -> index arithmetic
    const float* w1  = (const float*)d_in[4] + 1 * H_ * 2 * D_;  // k=1 slice
    const float* b1  = (const float*)d_in[5] + 1 * H_;
    const float* w2  = (const float*)d_in[6] + 1 * H_ * H_;
    const float* b2  = (const float*)d_in[7] + 1 * H_;
    const float* f1w = (const float*)d_in[8];
    const float* f1b = (const float*)d_in[9];
    const float* f2w = (const float*)d_in[10];
    const float* f2b = (const float*)d_in[11];
    const float* f3w = (const float*)d_in[12];
    const float* f3b = (const float*)d_in[13];
    float* out = (float*)d_out;

    unsigned char* ws = (unsigned char*)d_ws;   // needs 2,119,680 B
    float*  rtt = (float*)(ws + WS_RTT);
    __half* ubf = (__half*)(ws + WS_UBF);
    __half* w2f = (__half*)(ws + WS_W2F);
    __half* w1f = (__half*)(ws + WS_W1F);
    __half* w2b = (__half*)(ws + WS_W2B);
    __half* w3f = (__half*)(ws + WS_W3F);

    // tasks: 12000 u rows + 800 rtt rows + 29 frag waves = 12829 -> 3208 blocks
    nri_prep<<<dim3(3208), 256, 0, stream>>>(x, rel, w1, w2, f1w, f2w, f3w,
                                             ubf, rtt, w2f, w1f, w2b, w3f);
    nri_main<<<dim3(B_ * TP_ * NG2), 256, 0, stream>>>(
        ubf, rtt, w2f, b2, w1, b1, w1f, w2b, w3f, f1b, f2b, f3b, x, out);
}